// Round 13
// baseline (1615.764 us; speedup 1.0000x reference)
//
#include <hip/hip_runtime.h>

#define NT 1024
#define RINGS 256

typedef _Float16 half8 __attribute__((ext_vector_type(8)));
typedef _Float16 half4 __attribute__((ext_vector_type(4)));
typedef float f32x4 __attribute__((ext_vector_type(4)));
typedef unsigned long long u64;
struct U2 { u64 a, b; };

#ifndef __has_builtin
#define __has_builtin(x) 0
#endif

__device__ __forceinline__ f32x4 MFMA(half8 a, half8 b, f32x4 c) {
  return __builtin_amdgcn_mfma_f32_16x16x32_f16(a, b, c, 0, 0, 0);
}
__device__ __forceinline__ float exp2h(float x) {
#if __has_builtin(__builtin_amdgcn_exp2f)
  return __builtin_amdgcn_exp2f(x);
#else
  return exp2f(x);
#endif
}
__device__ __forceinline__ float sigf(float x) {
  return __builtin_amdgcn_rcpf(1.0f + exp2h(x * -1.44269504f));
}
__device__ __forceinline__ float tanhf2(float x) {
  float t = __builtin_amdgcn_rcpf(1.0f + exp2h(x * 2.88539008f));
  return fmaf(-2.0f, t, 1.0f);
}
__device__ __forceinline__ half8 cvt8(float4 c0, float4 c1) {
  half8 hv;
  hv[0] = (_Float16)c0.x; hv[1] = (_Float16)c0.y;
  hv[2] = (_Float16)c0.z; hv[3] = (_Float16)c0.w;
  hv[4] = (_Float16)c1.x; hv[5] = (_Float16)c1.y;
  hv[6] = (_Float16)c1.z; hv[7] = (_Float16)c1.w;
  return hv;
}
__device__ __forceinline__ half8 ldring(const _Float16* p) {
  const u64* q = (const u64*)p;
  U2 uu;
  uu.a = __hip_atomic_load(q, __ATOMIC_RELAXED, __HIP_MEMORY_SCOPE_AGENT);
  uu.b = __hip_atomic_load(q + 1, __ATOMIC_RELAXED, __HIP_MEMORY_SCOPE_AGENT);
  return __builtin_bit_cast(half8, uu);
}
__device__ __forceinline__ unsigned wpoll(unsigned* p, unsigned tgt,
                                          unsigned cached, int l) {
  unsigned c = cached;
  while (c < tgt) {
    unsigned pv = 0;
    if (l == 0)
      pv = __hip_atomic_load(p, __ATOMIC_ACQUIRE, __HIP_MEMORY_SCOPE_AGENT);
    c = (unsigned)__builtin_amdgcn_readfirstlane((int)pv);
    if (c < tgt) __builtin_amdgcn_s_sleep(2);
  }
  return c;
}

// Repack x [B,T,64] f32 -> f16 B-fragments Xf[g][t][kt][lane][8]
__global__ __launch_bounds__(256) void prep_x(const float* __restrict__ x,
                                              _Float16* __restrict__ Xf) {
  int t0 = blockIdx.x * 256 + threadIdx.x;
  int l = t0 & 63;
  int fid = t0 >> 6;                  // ((g*NT + t)*2 + kt)
  int kt = fid & 1;
  int t = (fid >> 1) & (NT - 1);
  int g = fid >> 11;
  int bt = g * 16 + (l & 15);
  int kb = kt * 32 + (l >> 4) * 4;
  const float* src = x + ((size_t)bt * NT + (size_t)t) * 64 + kb;
  float4 v0 = *(const float4*)src;
  float4 v1 = *(const float4*)(src + 16);
  *(half8*)(Xf + (size_t)fid * 512 + l * 8) = cvt8(v0, v1);
}

// 16 blocks x 1024 threads (16 waves, 4/SIMD). Blocks 0-7 layer-0, 8-15
// layer-1+FC (R6 ring handshake). Within a block, TWO concurrent wave-sets:
// waves 0-7 ("in-side") compute bias + W_in * input for step t+1 into a
// double-buffered LDS partial; waves 8-15 ("rec-side") do the hh-GEMM
// (acc-init from partial), cell, h-frag store. Halves per-wave serial work
// and doubles waves/SIMD for latency hiding.
#define BARRIER_LGKM()                              \
  asm volatile("s_waitcnt lgkmcnt(0)" ::: "memory"); \
  __builtin_amdgcn_sched_barrier(0);                 \
  __builtin_amdgcn_s_barrier();                      \
  __builtin_amdgcn_sched_barrier(0)

__global__ __launch_bounds__(1024, 1) void lstm_main(
    const float* __restrict__ wih0, const float* __restrict__ whh0,
    const float* __restrict__ wih1, const float* __restrict__ whh1,
    const float* __restrict__ bih, const float* __restrict__ bhh,
    const float* __restrict__ fcw, const float* __restrict__ fcb,
    const _Float16* __restrict__ Xf, _Float16* __restrict__ ringH0,
    unsigned* __restrict__ flags, float* __restrict__ out) {
  const int tid = threadIdx.x;
  const int w = tid >> 6, l = tid & 63;
  const int n = l & 15, lg = l >> 4;
  const bool producer = blockIdx.x < 8;
  const int g = blockIdx.x & 7;
  const int q = w & 7;  // quartet (gate M-tile group) this wave owns

  __shared__ _Float16 hfr[2][4][64][8];   // own-layer h frags (8 KB)
  __shared__ float pp[2][8][4][64][4];    // in-side partials (64 KB)

  _Float16* ringG = ringH0 + (size_t)g * RINGS * 2048;
  unsigned* prog = flags + g * 16;
  unsigned* cons = flags + (8 + g) * 16;
  const half8 hz = {0, 0, 0, 0, 0, 0, 0, 0};

  if (tid < 256) ((half8*)&hfr[1][0][0][0])[tid] = hz;  // h[-1] = 0

  if (producer) {
    if (w < 8) {
      // ======== xh-waves: pps(s+1) = bias + Wih0 x(s+1) ========
      half8 Ax[4][2];
      f32x4 bias[4];
#pragma unroll
      for (int gt = 0; gt < 4; ++gt) {
        int row = (q + 8 * gt) * 16 + n;
#pragma unroll
        for (int kt = 0; kt < 2; ++kt) {
          const float* wp = wih0 + (size_t)row * 64 + kt * 32 + lg * 4;
          Ax[gt][kt] = cvt8(*(const float4*)wp, *(const float4*)(wp + 16));
        }
        int rb = (q + 8 * gt) * 16 + lg * 4;
        f32x4 bv;
#pragma unroll
        for (int r = 0; r < 4; ++r) bv[r] = bih[rb + r] + bhh[rb + r];
        bias[gt] = bv;
      }
      const _Float16* XfG = Xf + (size_t)g * NT * 1024;
      half8 xv0 = *(const half8*)(XfG + l * 8);
      half8 xv1 = *(const half8*)(XfG + 512 + l * 8);
      {  // prologue: pp[0] = bias + Wx x(0)
        f32x4 a0 = MFMA(Ax[0][0], xv0, bias[0]);
        f32x4 a1 = MFMA(Ax[1][0], xv0, bias[1]);
        f32x4 a2 = MFMA(Ax[2][0], xv0, bias[2]);
        f32x4 a3 = MFMA(Ax[3][0], xv0, bias[3]);
        a0 = MFMA(Ax[0][1], xv1, a0); a1 = MFMA(Ax[1][1], xv1, a1);
        a2 = MFMA(Ax[2][1], xv1, a2); a3 = MFMA(Ax[3][1], xv1, a3);
        *(f32x4*)&pp[0][q][0][l][0] = a0;
        *(f32x4*)&pp[0][q][1][l][0] = a1;
        *(f32x4*)&pp[0][q][2][l][0] = a2;
        *(f32x4*)&pp[0][q][3][l][0] = a3;
      }
      xv0 = *(const half8*)(XfG + 1024 + l * 8);   // x(1)
      xv1 = *(const half8*)(XfG + 1024 + 512 + l * 8);
      unsigned Cc = 0;
      __syncthreads();
      for (int s = 0; s < NT; ++s) {
        if (s >= 224 && (s & 31) == 0)
          Cc = wpoll(cons, (unsigned)(s - 192), Cc, l);
        if (s + 1 < NT) {
          f32x4 a0 = MFMA(Ax[0][0], xv0, bias[0]);
          f32x4 a1 = MFMA(Ax[1][0], xv0, bias[1]);
          f32x4 a2 = MFMA(Ax[2][0], xv0, bias[2]);
          f32x4 a3 = MFMA(Ax[3][0], xv0, bias[3]);
          a0 = MFMA(Ax[0][1], xv1, a0); a1 = MFMA(Ax[1][1], xv1, a1);
          a2 = MFMA(Ax[2][1], xv1, a2); a3 = MFMA(Ax[3][1], xv1, a3);
          const int sl = (s + 1) & 1;
          *(f32x4*)&pp[sl][q][0][l][0] = a0;
          *(f32x4*)&pp[sl][q][1][l][0] = a1;
          *(f32x4*)&pp[sl][q][2][l][0] = a2;
          *(f32x4*)&pp[sl][q][3][l][0] = a3;
        }
        if (s + 2 < NT) {
          const _Float16* p = XfG + (size_t)(s + 2) * 1024 + l * 8;
          xv0 = *(const half8*)p;
          xv1 = *(const half8*)(p + 512);
        }
        BARRIER_LGKM();
        if ((s & 31) == 31) {
          asm volatile("s_waitcnt vmcnt(0)" ::: "memory");
          __builtin_amdgcn_sched_barrier(0);
          __builtin_amdgcn_s_barrier();
          __builtin_amdgcn_sched_barrier(0);
          if (tid == 0)
            __hip_atomic_store(prog, (unsigned)(s + 1), __ATOMIC_RELEASE,
                               __HIP_MEMORY_SCOPE_AGENT);
        }
      }
    } else {
      // ======== hc-waves: hh-GEMM + cell + hfr/ring store ========
      half8 Ah[4][4];
#pragma unroll
      for (int gt = 0; gt < 4; ++gt) {
        int row = (q + 8 * gt) * 16 + n;
#pragma unroll
        for (int kt = 0; kt < 4; ++kt) {
          const float* wp = whh0 + (size_t)row * 128 + kt * 32 + lg * 4;
          Ah[gt][kt] = cvt8(*(const float4*)wp, *(const float4*)(wp + 16));
        }
      }
      f32x4 cst = {0.f, 0.f, 0.f, 0.f};
      unsigned Cc = 0;
      __syncthreads();
      for (int s = 0; s < NT; ++s) {
        if (s >= 224 && (s & 31) == 0)
          Cc = wpoll(cons, (unsigned)(s - 192), Cc, l);
        const int rdk = (s + 1) & 1;
        half8 b0 = *(const half8*)&hfr[rdk][0][l][0];
        half8 b1 = *(const half8*)&hfr[rdk][1][l][0];
        half8 b2 = *(const half8*)&hfr[rdk][2][l][0];
        half8 b3 = *(const half8*)&hfr[rdk][3][l][0];
        f32x4 c0 = *(const f32x4*)&pp[s & 1][q][0][l][0];
        f32x4 c1 = *(const f32x4*)&pp[s & 1][q][1][l][0];
        f32x4 c2 = *(const f32x4*)&pp[s & 1][q][2][l][0];
        f32x4 c3 = *(const f32x4*)&pp[s & 1][q][3][l][0];
        c0 = MFMA(Ah[0][0], b0, c0); c1 = MFMA(Ah[1][0], b0, c1);
        c2 = MFMA(Ah[2][0], b0, c2); c3 = MFMA(Ah[3][0], b0, c3);
        c0 = MFMA(Ah[0][1], b1, c0); c1 = MFMA(Ah[1][1], b1, c1);
        c2 = MFMA(Ah[2][1], b1, c2); c3 = MFMA(Ah[3][1], b1, c3);
        c0 = MFMA(Ah[0][2], b2, c0); c1 = MFMA(Ah[1][2], b2, c1);
        c2 = MFMA(Ah[2][2], b2, c2); c3 = MFMA(Ah[3][2], b2, c3);
        c0 = MFMA(Ah[0][3], b3, c0); c1 = MFMA(Ah[1][3], b3, c1);
        c2 = MFMA(Ah[2][3], b3, c2); c3 = MFMA(Ah[3][3], b3, c3);
        half4 hh;
#pragma unroll
        for (int r = 0; r < 4; ++r) {
          float iv = sigf(c0[r]), fv = sigf(c1[r]);
          float gv = tanhf2(c2[r]), ov = sigf(c3[r]);
          cst[r] = fv * cst[r] + iv * gv;
          hh[r] = (_Float16)(ov * tanhf2(cst[r]));
        }
        *(half4*)&hfr[s & 1][q >> 1][l][(q & 1) << 2] = hh;
        u64 uh = __builtin_bit_cast(u64, hh);
        __hip_atomic_store(
            (u64*)(ringG + (size_t)(s & (RINGS - 1)) * 2048 +
                   (q >> 1) * 512 + l * 8 + (q & 1) * 4),
            uh, __ATOMIC_RELAXED, __HIP_MEMORY_SCOPE_AGENT);
        BARRIER_LGKM();
        if ((s & 31) == 31) {
          asm volatile("s_waitcnt vmcnt(0)" ::: "memory");
          __builtin_amdgcn_sched_barrier(0);
          __builtin_amdgcn_s_barrier();
          __builtin_amdgcn_sched_barrier(0);
          // publish done by tid==0 (xh side)
        }
      }
    }
  } else {
    if (w < 8) {
      // ======== ih-waves: pis(t+1) = bias + Wih1 h0(t+1) ========
      half8 Ai[4][4];
      f32x4 bias[4];
#pragma unroll
      for (int gt = 0; gt < 4; ++gt) {
        int row = (q + 8 * gt) * 16 + n;
#pragma unroll
        for (int kt = 0; kt < 4; ++kt) {
          const float* wp = wih1 + (size_t)row * 128 + kt * 32 + lg * 4;
          Ai[gt][kt] = cvt8(*(const float4*)wp, *(const float4*)(wp + 16));
        }
        int rb = (q + 8 * gt) * 16 + lg * 4;
        f32x4 bv;
#pragma unroll
        for (int r = 0; r < 4; ++r)
          bv[r] = bih[512 + rb + r] + bhh[512 + rb + r];
        bias[gt] = bv;
      }
      unsigned Pc = wpoll(prog, 2u, 0u, l);
      half8 t0 = ldring(ringG + l * 8);          // h0[0]
      half8 t1 = ldring(ringG + 512 + l * 8);
      half8 t2 = ldring(ringG + 1024 + l * 8);
      half8 t3 = ldring(ringG + 1536 + l * 8);
      {  // prologue: pp[0] = bias + Wih1 h0[0]
        f32x4 a0 = MFMA(Ai[0][0], t0, bias[0]);
        f32x4 a1 = MFMA(Ai[1][0], t0, bias[1]);
        f32x4 a2 = MFMA(Ai[2][0], t0, bias[2]);
        f32x4 a3 = MFMA(Ai[3][0], t0, bias[3]);
        a0 = MFMA(Ai[0][1], t1, a0); a1 = MFMA(Ai[1][1], t1, a1);
        a2 = MFMA(Ai[2][1], t1, a2); a3 = MFMA(Ai[3][1], t1, a3);
        a0 = MFMA(Ai[0][2], t2, a0); a1 = MFMA(Ai[1][2], t2, a1);
        a2 = MFMA(Ai[2][2], t2, a2); a3 = MFMA(Ai[3][2], t2, a3);
        a0 = MFMA(Ai[0][3], t3, a0); a1 = MFMA(Ai[1][3], t3, a1);
        a2 = MFMA(Ai[2][3], t3, a2); a3 = MFMA(Ai[3][3], t3, a3);
        *(f32x4*)&pp[0][q][0][l][0] = a0;
        *(f32x4*)&pp[0][q][1][l][0] = a1;
        *(f32x4*)&pp[0][q][2][l][0] = a2;
        *(f32x4*)&pp[0][q][3][l][0] = a3;
      }
      const _Float16* rb1 = ringG + 2048 + l * 8;  // h0[1]
      half8 HC0 = ldring(rb1);
      half8 HC1 = ldring(rb1 + 512);
      half8 HC2 = ldring(rb1 + 1024);
      half8 HC3 = ldring(rb1 + 1536);
      __syncthreads();
      for (int t = 0; t < NT; ++t) {
        if (t + 1 < NT) {
          f32x4 a0 = MFMA(Ai[0][0], HC0, bias[0]);
          f32x4 a1 = MFMA(Ai[1][0], HC0, bias[1]);
          f32x4 a2 = MFMA(Ai[2][0], HC0, bias[2]);
          f32x4 a3 = MFMA(Ai[3][0], HC0, bias[3]);
          a0 = MFMA(Ai[0][1], HC1, a0); a1 = MFMA(Ai[1][1], HC1, a1);
          a2 = MFMA(Ai[2][1], HC1, a2); a3 = MFMA(Ai[3][1], HC1, a3);
          a0 = MFMA(Ai[0][2], HC2, a0); a1 = MFMA(Ai[1][2], HC2, a1);
          a2 = MFMA(Ai[2][2], HC2, a2); a3 = MFMA(Ai[3][2], HC2, a3);
          a0 = MFMA(Ai[0][3], HC3, a0); a1 = MFMA(Ai[1][3], HC3, a1);
          a2 = MFMA(Ai[2][3], HC3, a2); a3 = MFMA(Ai[3][3], HC3, a3);
          const int sl = (t + 1) & 1;
          *(f32x4*)&pp[sl][q][0][l][0] = a0;
          *(f32x4*)&pp[sl][q][1][l][0] = a1;
          *(f32x4*)&pp[sl][q][2][l][0] = a2;
          *(f32x4*)&pp[sl][q][3][l][0] = a3;
        }
        if (t + 2 < NT) {
          Pc = wpoll(prog, (unsigned)(t + 3), Pc, l);
          const _Float16* rb_ =
              ringG + (size_t)((t + 2) & (RINGS - 1)) * 2048 + l * 8;
          HC0 = ldring(rb_);
          HC1 = ldring(rb_ + 512);
          HC2 = ldring(rb_ + 1024);
          HC3 = ldring(rb_ + 1536);
        }
        BARRIER_LGKM();
      }
    } else {
      // ======== hhc-waves: hh-GEMM + cell + FC + out ========
      half8 Ah[4][4], FCA[4];
      f32x4 fcbv = {0.f, 0.f, 0.f, 0.f};
#pragma unroll
      for (int gt = 0; gt < 4; ++gt) {
        int row = (q + 8 * gt) * 16 + n;
#pragma unroll
        for (int kt = 0; kt < 4; ++kt) {
          const float* wp = whh1 + (size_t)row * 128 + kt * 32 + lg * 4;
          Ah[gt][kt] = cvt8(*(const float4*)wp, *(const float4*)(wp + 16));
        }
      }
      const bool fcw_ = (q < 4);
      if (fcw_) {
        int frow = (q << 4) + n;
#pragma unroll
        for (int kt = 0; kt < 4; ++kt) {
          const float* wp = fcw + (size_t)frow * 128 + kt * 32 + lg * 4;
          FCA[kt] = cvt8(*(const float4*)wp, *(const float4*)(wp + 16));
        }
        fcbv = *(const f32x4*)(fcb + (q << 4) + lg * 4);
      }
      float* outG = out + (size_t)((g << 4) + n) * NT * 64 + (q << 4) + lg * 4;
      f32x4 cst = {0.f, 0.f, 0.f, 0.f};
      __syncthreads();
      for (int t = 0; t < NT; ++t) {
        const int rdk = (t + 1) & 1;
        half8 b0 = *(const half8*)&hfr[rdk][0][l][0];
        half8 b1 = *(const half8*)&hfr[rdk][1][l][0];
        half8 b2 = *(const half8*)&hfr[rdk][2][l][0];
        half8 b3 = *(const half8*)&hfr[rdk][3][l][0];
        f32x4 c0 = *(const f32x4*)&pp[t & 1][q][0][l][0];
        f32x4 c1 = *(const f32x4*)&pp[t & 1][q][1][l][0];
        f32x4 c2 = *(const f32x4*)&pp[t & 1][q][2][l][0];
        f32x4 c3 = *(const f32x4*)&pp[t & 1][q][3][l][0];
        c0 = MFMA(Ah[0][0], b0, c0); c1 = MFMA(Ah[1][0], b0, c1);
        c2 = MFMA(Ah[2][0], b0, c2); c3 = MFMA(Ah[3][0], b0, c3);
        c0 = MFMA(Ah[0][1], b1, c0); c1 = MFMA(Ah[1][1], b1, c1);
        c2 = MFMA(Ah[2][1], b1, c2); c3 = MFMA(Ah[3][1], b1, c3);
        c0 = MFMA(Ah[0][2], b2, c0); c1 = MFMA(Ah[1][2], b2, c1);
        c2 = MFMA(Ah[2][2], b2, c2); c3 = MFMA(Ah[3][2], b2, c3);
        c0 = MFMA(Ah[0][3], b3, c0); c1 = MFMA(Ah[1][3], b3, c1);
        c2 = MFMA(Ah[2][3], b3, c2); c3 = MFMA(Ah[3][3], b3, c3);
        if (fcw_) {  // FC of h1[t-1]
          f32x4 afc = fcbv;
          afc = MFMA(FCA[0], b0, afc); afc = MFMA(FCA[1], b1, afc);
          afc = MFMA(FCA[2], b2, afc); afc = MFMA(FCA[3], b3, afc);
          if (t >= 1) *(f32x4*)(outG + (size_t)(t - 1) * 64) = afc;
        }
        half4 hh;
#pragma unroll
        for (int r = 0; r < 4; ++r) {
          float iv = sigf(c0[r]), fv = sigf(c1[r]);
          float gv = tanhf2(c2[r]), ov = sigf(c3[r]);
          cst[r] = fv * cst[r] + iv * gv;
          hh[r] = (_Float16)(ov * tanhf2(cst[r]));
        }
        *(half4*)&hfr[t & 1][q >> 1][l][(q & 1) << 2] = hh;
        if (tid == 512 && (t & 31) == 0)
          __hip_atomic_store(cons, (unsigned)t, __ATOMIC_RELAXED,
                             __HIP_MEMORY_SCOPE_AGENT);
        BARRIER_LGKM();
      }
      {  // epilogue: FC of h1[NT-1]
        const int rdk = (NT + 1) & 1;
        half8 b0 = *(const half8*)&hfr[rdk][0][l][0];
        half8 b1 = *(const half8*)&hfr[rdk][1][l][0];
        half8 b2 = *(const half8*)&hfr[rdk][2][l][0];
        half8 b3 = *(const half8*)&hfr[rdk][3][l][0];
        if (fcw_) {
          f32x4 afc = fcbv;
          afc = MFMA(FCA[0], b0, afc); afc = MFMA(FCA[1], b1, afc);
          afc = MFMA(FCA[2], b2, afc); afc = MFMA(FCA[3], b3, afc);
          *(f32x4*)(outG + (size_t)(NT - 1) * 64) = afc;
        }
      }
    }
  }
}

extern "C" void kernel_launch(void* const* d_in, const int* in_sizes, int n_in,
                              void* d_out, int out_size, void* d_ws, size_t ws_size,
                              hipStream_t stream) {
  const float* x     = (const float*)d_in[0];
  const float* w_ih0 = (const float*)d_in[1];
  const float* w_hh0 = (const float*)d_in[2];
  const float* w_ih1 = (const float*)d_in[3];
  const float* w_hh1 = (const float*)d_in[4];
  const float* b_ih  = (const float*)d_in[5];
  const float* b_hh  = (const float*)d_in[6];
  const float* fc_w  = (const float*)d_in[7];
  const float* fc_b  = (const float*)d_in[8];

  _Float16* Xf   = (_Float16*)d_ws;                           // 16 MB
  _Float16* ring = (_Float16*)((char*)d_ws + (16u << 20));    // 8 MB
  unsigned* flags = (unsigned*)((char*)d_ws + (24u << 20));   // 4 KB

  (void)hipMemsetAsync(flags, 0, 4096, stream);
  prep_x<<<4096, 256, 0, stream>>>(x, Xf);
  lstm_main<<<16, 1024, 0, stream>>>(w_ih0, w_hh0, w_ih1, w_hh1, b_ih, b_hh,
                                     fc_w, fc_b, Xf, ring, flags,
                                     (float*)d_out);
}

// Round 15
// 1231.100 us; speedup vs baseline: 1.3125x; 1.3125x over previous
//
#include <hip/hip_runtime.h>

#define NT 1024
#define H0S 256
#define GS 64
#define LAG 32

typedef _Float16 half8 __attribute__((ext_vector_type(8)));
typedef _Float16 half4 __attribute__((ext_vector_type(4)));
typedef float f32x4 __attribute__((ext_vector_type(4)));
typedef unsigned long long u64;

#ifndef __has_builtin
#define __has_builtin(x) 0
#endif

__device__ __forceinline__ f32x4 MFMA(half8 a, half8 b, f32x4 c) {
  return __builtin_amdgcn_mfma_f32_16x16x32_f16(a, b, c, 0, 0, 0);
}
__device__ __forceinline__ float exp2h(float x) {
#if __has_builtin(__builtin_amdgcn_exp2f)
  return __builtin_amdgcn_exp2f(x);
#else
  return exp2f(x);
#endif
}
__device__ __forceinline__ float sigf(float x) {
  return __builtin_amdgcn_rcpf(1.0f + exp2h(x * -1.44269504f));
}
__device__ __forceinline__ float tanhf2(float x) {
  float t = __builtin_amdgcn_rcpf(1.0f + exp2h(x * 2.88539008f));
  return fmaf(-2.0f, t, 1.0f);
}
__device__ __forceinline__ half8 cvt8(float4 c0, float4 c1) {
  half8 hv;
  hv[0] = (_Float16)c0.x; hv[1] = (_Float16)c0.y;
  hv[2] = (_Float16)c0.z; hv[3] = (_Float16)c0.w;
  hv[4] = (_Float16)c1.x; hv[5] = (_Float16)c1.y;
  hv[6] = (_Float16)c1.z; hv[7] = (_Float16)c1.w;
  return hv;
}
__device__ __forceinline__ unsigned wpoll(unsigned* p, unsigned tgt,
                                          unsigned cached, int l) {
  unsigned c = cached;
  while (c < tgt) {
    unsigned pv = 0;
    if (l == 0)
      pv = __hip_atomic_load(p, __ATOMIC_ACQUIRE, __HIP_MEMORY_SCOPE_AGENT);
    c = (unsigned)__builtin_amdgcn_readfirstlane((int)pv);
    if (c < tgt) __builtin_amdgcn_s_sleep(2);
  }
  return c;
}

#define DRAIN_BARRIER()                              \
  asm volatile("s_waitcnt vmcnt(0)" ::: "memory");   \
  __builtin_amdgcn_sched_barrier(0);                 \
  __builtin_amdgcn_s_barrier();                      \
  __builtin_amdgcn_sched_barrier(0)

#define LGKM_BARRIER()                               \
  asm volatile("s_waitcnt lgkmcnt(0)" ::: "memory"); \
  __builtin_amdgcn_sched_barrier(0);                 \
  __builtin_amdgcn_s_barrier();                      \
  __builtin_amdgcn_sched_barrier(0)

// Repack x [B,T,64] f32 -> f16 B-fragments Xf[g][t][kt][lane][8]
__global__ __launch_bounds__(256) void prep_x(const float* __restrict__ x,
                                              _Float16* __restrict__ Xf) {
  int t0 = blockIdx.x * 256 + threadIdx.x;
  int l = t0 & 63;
  int fid = t0 >> 6;                  // ((g*NT + t)*2 + kt)
  int kt = fid & 1;
  int t = (fid >> 1) & (NT - 1);
  int g = fid >> 11;
  int bt = g * 16 + (l & 15);
  int kb = kt * 32 + (l >> 4) * 4;
  const float* src = x + ((size_t)bt * NT + (size_t)t) * 64 + kb;
  float4 v0 = *(const float4*)src;
  float4 v1 = *(const float4*)(src + 16);
  *(half8*)(Xf + (size_t)fid * 512 + l * 8) = cvt8(v0, v1);
}

// 24 blocks x 512 threads. role = bid>>3: 0 = X (input-side GEMMs gx0,gy1),
// 1 = P (layer-0 recurrence, hh only), 2 = Y (layer-1 recurrence + FC).
// LAG=32 (deadlock bound is 17 at publish-granularity 8; R14's LAG=12 hung).
// Ring DATA = plain coalesced vector ops; cross-CU visibility via drained
// release flags + acquire polls (R6-proven).
__global__ __launch_bounds__(512, 1) void lstm_main(
    const float* __restrict__ wih0, const float* __restrict__ whh0,
    const float* __restrict__ wih1, const float* __restrict__ whh1,
    const float* __restrict__ bih, const float* __restrict__ bhh,
    const float* __restrict__ fcw, const float* __restrict__ fcb,
    const _Float16* __restrict__ Xf, _Float16* __restrict__ h0R,
    float* __restrict__ gxR, float* __restrict__ gyR,
    unsigned* __restrict__ flags, float* __restrict__ out) {
  const int tid = threadIdx.x;
  const int w = tid >> 6, l = tid & 63;
  const int n = l & 15, lg = l >> 4;
  const int role = blockIdx.x >> 3;
  const int g = blockIdx.x & 7;

  __shared__ _Float16 hfr[2][4][64][8];

  _Float16* h0G = h0R + (size_t)g * H0S * 2048;
  float* gxG = gxR + (size_t)g * GS * 8192;
  float* gyG = gyR + (size_t)g * GS * 8192;
  unsigned* pX  = flags + (0 * 8 + g) * 16;
  unsigned* pXY = flags + (1 * 8 + g) * 16;
  unsigned* pP  = flags + (2 * 8 + g) * 16;
  unsigned* pY  = flags + (3 * 8 + g) * 16;
  const half8 hz = {0, 0, 0, 0, 0, 0, 0, 0};

  if (role == 0) {
    // ================= X: gx0[s] & gy1[u=s-LAG] GEMMs =================
    half8 Ax[4][2], Ai[4][4];
    f32x4 b0v[4], b1v[4];
#pragma unroll
    for (int q = 0; q < 4; ++q) {
      int row = (w + 8 * q) * 16 + n;
#pragma unroll
      for (int kt = 0; kt < 2; ++kt) {
        const float* wp = wih0 + (size_t)row * 64 + kt * 32 + lg * 4;
        Ax[q][kt] = cvt8(*(const float4*)wp, *(const float4*)(wp + 16));
      }
#pragma unroll
      for (int kt = 0; kt < 4; ++kt) {
        const float* wp = wih1 + (size_t)row * 128 + kt * 32 + lg * 4;
        Ai[q][kt] = cvt8(*(const float4*)wp, *(const float4*)(wp + 16));
      }
      int rb = (w + 8 * q) * 16 + lg * 4;
      f32x4 v0, v1;
#pragma unroll
      for (int r = 0; r < 4; ++r) {
        v0[r] = bih[rb + r] + bhh[rb + r];
        v1[r] = bih[512 + rb + r] + bhh[512 + rb + r];
      }
      b0v[q] = v0;
      b1v[q] = v1;
    }
    const _Float16* XfG = Xf + (size_t)g * NT * 1024;
    half8 xv0 = *(const half8*)(XfG + l * 8);
    half8 xv1 = *(const half8*)(XfG + 512 + l * 8);
    half8 hb0 = hz, hb1 = hz, hb2 = hz, hb3 = hz;
    unsigned Pp = 0, Yp = 0;
    for (int s = 0; s < NT + LAG; ++s) {
      const int u = s - LAG;
      if (s < NT) {  // gx0[s]
        f32x4 a0 = MFMA(Ax[0][0], xv0, b0v[0]);
        f32x4 a1 = MFMA(Ax[1][0], xv0, b0v[1]);
        f32x4 a2 = MFMA(Ax[2][0], xv0, b0v[2]);
        f32x4 a3 = MFMA(Ax[3][0], xv0, b0v[3]);
        a0 = MFMA(Ax[0][1], xv1, a0); a1 = MFMA(Ax[1][1], xv1, a1);
        a2 = MFMA(Ax[2][1], xv1, a2); a3 = MFMA(Ax[3][1], xv1, a3);
        float* gp = gxG + (size_t)(s & (GS - 1)) * 8192;
        *(f32x4*)(gp + ((0 + w) * 64 + l) * 4) = a0;
        *(f32x4*)(gp + ((8 + w) * 64 + l) * 4) = a1;
        *(f32x4*)(gp + ((16 + w) * 64 + l) * 4) = a2;
        *(f32x4*)(gp + ((24 + w) * 64 + l) * 4) = a3;
        if (s + 1 < NT) {
          const _Float16* p = XfG + (size_t)(s + 1) * 1024 + l * 8;
          xv0 = *(const half8*)p;
          xv1 = *(const half8*)(p + 512);
        }
      }
      if (u >= 0) {  // gy1[u] = b1 + Wih1 h0[u]
        if (u == 0) {  // cold load h0[0]
          Pp = wpoll(pP, 1u, Pp, l);
          const _Float16* hp = h0G + l * 8;
          hb0 = *(const half8*)hp;
          hb1 = *(const half8*)(hp + 512);
          hb2 = *(const half8*)(hp + 1024);
          hb3 = *(const half8*)(hp + 1536);
        }
        f32x4 c0 = MFMA(Ai[0][0], hb0, b1v[0]);
        f32x4 c1 = MFMA(Ai[1][0], hb0, b1v[1]);
        f32x4 c2 = MFMA(Ai[2][0], hb0, b1v[2]);
        f32x4 c3 = MFMA(Ai[3][0], hb0, b1v[3]);
        c0 = MFMA(Ai[0][1], hb1, c0); c1 = MFMA(Ai[1][1], hb1, c1);
        c2 = MFMA(Ai[2][1], hb1, c2); c3 = MFMA(Ai[3][1], hb1, c3);
        c0 = MFMA(Ai[0][2], hb2, c0); c1 = MFMA(Ai[1][2], hb2, c1);
        c2 = MFMA(Ai[2][2], hb2, c2); c3 = MFMA(Ai[3][2], hb2, c3);
        c0 = MFMA(Ai[0][3], hb3, c0); c1 = MFMA(Ai[1][3], hb3, c1);
        c2 = MFMA(Ai[2][3], hb3, c2); c3 = MFMA(Ai[3][3], hb3, c3);
        float* gp = gyG + (size_t)(u & (GS - 1)) * 8192;
        *(f32x4*)(gp + ((0 + w) * 64 + l) * 4) = c0;
        *(f32x4*)(gp + ((8 + w) * 64 + l) * 4) = c1;
        *(f32x4*)(gp + ((16 + w) * 64 + l) * 4) = c2;
        *(f32x4*)(gp + ((24 + w) * 64 + l) * 4) = c3;
        if (u + 1 < NT) {  // prefetch h0[u+1]
          Pp = wpoll(pP, (unsigned)(u + 2), Pp, l);
          const _Float16* hp =
              h0G + (size_t)((u + 1) & (H0S - 1)) * 2048 + l * 8;
          hb0 = *(const half8*)hp;
          hb1 = *(const half8*)(hp + 512);
          hb2 = *(const half8*)(hp + 1024);
          hb3 = *(const half8*)(hp + 1536);
        }
        if ((u & 15) == 0 && u >= 56)  // gy ring backpressure vs Y
          Yp = wpoll(pY, (unsigned)(u - 48), Yp, l);
      }
      if ((s & 7) == 7) {  // drained release publish (both rings)
        DRAIN_BARRIER();
        if (tid == 0) {
          __hip_atomic_store(pX, (unsigned)(s + 1), __ATOMIC_RELEASE,
                             __HIP_MEMORY_SCOPE_AGENT);
          if (u >= 0)
            __hip_atomic_store(pXY, (unsigned)(u + 1), __ATOMIC_RELEASE,
                               __HIP_MEMORY_SCOPE_AGENT);
        }
      }
    }
    DRAIN_BARRIER();
    if (tid == 0) {
      __hip_atomic_store(pX, (unsigned)(NT + LAG), __ATOMIC_RELEASE,
                         __HIP_MEMORY_SCOPE_AGENT);
      __hip_atomic_store(pXY, (unsigned)(NT + LAG), __ATOMIC_RELEASE,
                         __HIP_MEMORY_SCOPE_AGENT);
    }
  } else if (role == 1) {
    // ========== P: layer-0 recurrence (hh only, 16 MFMA/wave) ==========
    half8 Ah[4][4];
#pragma unroll
    for (int q = 0; q < 4; ++q) {
      int row = (w + 8 * q) * 16 + n;
#pragma unroll
      for (int kt = 0; kt < 4; ++kt) {
        const float* wp = whh0 + (size_t)row * 128 + kt * 32 + lg * 4;
        Ah[q][kt] = cvt8(*(const float4*)wp, *(const float4*)(wp + 16));
      }
    }
    if (tid < 256) ((half8*)&hfr[1][0][0][0])[tid] = hz;  // h0[-1]=0
    f32x4 cst = {0.f, 0.f, 0.f, 0.f};
    unsigned Xp = wpoll(pX, 2u, 0u, l);
    f32x4 gA0 = *(const f32x4*)(gxG + ((0 + w) * 64 + l) * 4);
    f32x4 gA1 = *(const f32x4*)(gxG + ((8 + w) * 64 + l) * 4);
    f32x4 gA2 = *(const f32x4*)(gxG + ((16 + w) * 64 + l) * 4);
    f32x4 gA3 = *(const f32x4*)(gxG + ((24 + w) * 64 + l) * 4);
    const float* g1 = gxG + 8192;
    f32x4 gB0 = *(const f32x4*)(g1 + ((0 + w) * 64 + l) * 4);
    f32x4 gB1 = *(const f32x4*)(g1 + ((8 + w) * 64 + l) * 4);
    f32x4 gB2 = *(const f32x4*)(g1 + ((16 + w) * 64 + l) * 4);
    f32x4 gB3 = *(const f32x4*)(g1 + ((24 + w) * 64 + l) * 4);
    __syncthreads();

#define PSTEP(T, G0, G1, G2, G3)                                               \
  {                                                                            \
    const int rdk_ = ((T) + 1) & 1;                                            \
    half8 b0 = *(const half8*)&hfr[rdk_][0][l][0];                             \
    half8 b1 = *(const half8*)&hfr[rdk_][1][l][0];                             \
    half8 b2 = *(const half8*)&hfr[rdk_][2][l][0];                             \
    half8 b3 = *(const half8*)&hfr[rdk_][3][l][0];                             \
    f32x4 c0 = G0, c1 = G1, c2 = G2, c3 = G3;                                  \
    c0 = MFMA(Ah[0][0], b0, c0); c1 = MFMA(Ah[1][0], b0, c1);                  \
    c2 = MFMA(Ah[2][0], b0, c2); c3 = MFMA(Ah[3][0], b0, c3);                  \
    c0 = MFMA(Ah[0][1], b1, c0); c1 = MFMA(Ah[1][1], b1, c1);                  \
    c2 = MFMA(Ah[2][1], b1, c2); c3 = MFMA(Ah[3][1], b1, c3);                  \
    c0 = MFMA(Ah[0][2], b2, c0); c1 = MFMA(Ah[1][2], b2, c1);                  \
    c2 = MFMA(Ah[2][2], b2, c2); c3 = MFMA(Ah[3][2], b2, c3);                  \
    c0 = MFMA(Ah[0][3], b3, c0); c1 = MFMA(Ah[1][3], b3, c1);                  \
    c2 = MFMA(Ah[2][3], b3, c2); c3 = MFMA(Ah[3][3], b3, c3);                  \
    if ((T) + 2 < NT) { /* prefetch gx[T+2] (plain, flies over barrier) */     \
      Xp = wpoll(pX, (unsigned)((T) + 3), Xp, l);                              \
      const float* gp_ = gxG + (size_t)(((T) + 2) & (GS - 1)) * 8192;          \
      G0 = *(const f32x4*)(gp_ + ((0 + w) * 64 + l) * 4);                      \
      G1 = *(const f32x4*)(gp_ + ((8 + w) * 64 + l) * 4);                      \
      G2 = *(const f32x4*)(gp_ + ((16 + w) * 64 + l) * 4);                     \
      G3 = *(const f32x4*)(gp_ + ((24 + w) * 64 + l) * 4);                     \
    }                                                                          \
    half4 hh;                                                                  \
    _Pragma("unroll")                                                          \
    for (int r = 0; r < 4; ++r) {                                              \
      float iv = sigf(c0[r]), fv = sigf(c1[r]);                                \
      float gv = tanhf2(c2[r]), ov = sigf(c3[r]);                              \
      cst[r] = fv * cst[r] + iv * gv;                                          \
      hh[r] = (_Float16)(ov * tanhf2(cst[r]));                                 \
    }                                                                          \
    *(half4*)&hfr[(T) & 1][w >> 1][l][(w & 1) << 2] = hh;                      \
    *(u64*)(h0G + (size_t)((T) & (H0S - 1)) * 2048 + (w >> 1) * 512 + l * 8 +  \
            (w & 1) * 4) = __builtin_bit_cast(u64, hh);                        \
    LGKM_BARRIER();                                                            \
    if (((T) & 7) == 7) {                                                      \
      DRAIN_BARRIER();                                                         \
      if (tid == 0)                                                            \
        __hip_atomic_store(pP, (unsigned)((T) + 1), __ATOMIC_RELEASE,          \
                           __HIP_MEMORY_SCOPE_AGENT);                          \
    }                                                                          \
  }

    for (int s = 0; s < NT; s += 2) {
      PSTEP(s, gA0, gA1, gA2, gA3);
      PSTEP(s + 1, gB0, gB1, gB2, gB3);
    }
#undef PSTEP
  } else {
    // ======= Y: layer-1 recurrence (hh, 16 MFMA/wave) + FC + out =======
    half8 Ah[4][4], FCA[4];
    f32x4 fcbv = {0.f, 0.f, 0.f, 0.f};
#pragma unroll
    for (int q = 0; q < 4; ++q) {
      int row = (w + 8 * q) * 16 + n;
#pragma unroll
      for (int kt = 0; kt < 4; ++kt) {
        const float* wp = whh1 + (size_t)row * 128 + kt * 32 + lg * 4;
        Ah[q][kt] = cvt8(*(const float4*)wp, *(const float4*)(wp + 16));
      }
    }
    const bool fcon = (w < 4);
    if (fcon) {
      int frow = (w << 4) + n;
#pragma unroll
      for (int kt = 0; kt < 4; ++kt) {
        const float* wp = fcw + (size_t)frow * 128 + kt * 32 + lg * 4;
        FCA[kt] = cvt8(*(const float4*)wp, *(const float4*)(wp + 16));
      }
      fcbv = *(const f32x4*)(fcb + (w << 4) + lg * 4);
    }
    if (tid < 256) ((half8*)&hfr[1][0][0][0])[tid] = hz;  // h1[-1]=0
    float* outG = out + (size_t)((g << 4) + n) * NT * 64 + (w << 4) + lg * 4;
    f32x4 cst = {0.f, 0.f, 0.f, 0.f};
    unsigned XYp = wpoll(pXY, 2u, 0u, l);
    f32x4 gA0 = *(const f32x4*)(gyG + ((0 + w) * 64 + l) * 4);
    f32x4 gA1 = *(const f32x4*)(gyG + ((8 + w) * 64 + l) * 4);
    f32x4 gA2 = *(const f32x4*)(gyG + ((16 + w) * 64 + l) * 4);
    f32x4 gA3 = *(const f32x4*)(gyG + ((24 + w) * 64 + l) * 4);
    const float* g1 = gyG + 8192;
    f32x4 gB0 = *(const f32x4*)(g1 + ((0 + w) * 64 + l) * 4);
    f32x4 gB1 = *(const f32x4*)(g1 + ((8 + w) * 64 + l) * 4);
    f32x4 gB2 = *(const f32x4*)(g1 + ((16 + w) * 64 + l) * 4);
    f32x4 gB3 = *(const f32x4*)(g1 + ((24 + w) * 64 + l) * 4);
    __syncthreads();

#define YSTEP(T, G0, G1, G2, G3)                                               \
  {                                                                            \
    const int rdk_ = ((T) + 1) & 1;                                            \
    half8 b0 = *(const half8*)&hfr[rdk_][0][l][0];                             \
    half8 b1 = *(const half8*)&hfr[rdk_][1][l][0];                             \
    half8 b2 = *(const half8*)&hfr[rdk_][2][l][0];                             \
    half8 b3 = *(const half8*)&hfr[rdk_][3][l][0];                             \
    f32x4 c0 = G0, c1 = G1, c2 = G2, c3 = G3;                                  \
    c0 = MFMA(Ah[0][0], b0, c0); c1 = MFMA(Ah[1][0], b0, c1);                  \
    c2 = MFMA(Ah[2][0], b0, c2); c3 = MFMA(Ah[3][0], b0, c3);                  \
    c0 = MFMA(Ah[0][1], b1, c0); c1 = MFMA(Ah[1][1], b1, c1);                  \
    c2 = MFMA(Ah[2][1], b1, c2); c3 = MFMA(Ah[3][1], b1, c3);                  \
    c0 = MFMA(Ah[0][2], b2, c0); c1 = MFMA(Ah[1][2], b2, c1);                  \
    c2 = MFMA(Ah[2][2], b2, c2); c3 = MFMA(Ah[3][2], b2, c3);                  \
    c0 = MFMA(Ah[0][3], b3, c0); c1 = MFMA(Ah[1][3], b3, c1);                  \
    c2 = MFMA(Ah[2][3], b3, c2); c3 = MFMA(Ah[3][3], b3, c3);                  \
    if (fcon) { /* FC of h1[T-1] */                                            \
      f32x4 afc = fcbv;                                                        \
      afc = MFMA(FCA[0], b0, afc); afc = MFMA(FCA[1], b1, afc);                \
      afc = MFMA(FCA[2], b2, afc); afc = MFMA(FCA[3], b3, afc);                \
      if ((T) >= 1) *(f32x4*)(outG + (size_t)((T) - 1) * 64) = afc;            \
    }                                                                          \
    if ((T) + 2 < NT) { /* prefetch gy[T+2] */                                 \
      XYp = wpoll(pXY, (unsigned)((T) + 3), XYp, l);                           \
      const float* gp_ = gyG + (size_t)(((T) + 2) & (GS - 1)) * 8192;          \
      G0 = *(const f32x4*)(gp_ + ((0 + w) * 64 + l) * 4);                      \
      G1 = *(const f32x4*)(gp_ + ((8 + w) * 64 + l) * 4);                      \
      G2 = *(const f32x4*)(gp_ + ((16 + w) * 64 + l) * 4);                     \
      G3 = *(const f32x4*)(gp_ + ((24 + w) * 64 + l) * 4);                     \
    }                                                                          \
    half4 hh;                                                                  \
    _Pragma("unroll")                                                          \
    for (int r = 0; r < 4; ++r) {                                              \
      float iv = sigf(c0[r]), fv = sigf(c1[r]);                                \
      float gv = tanhf2(c2[r]), ov = sigf(c3[r]);                              \
      cst[r] = fv * cst[r] + iv * gv;                                          \
      hh[r] = (_Float16)(ov * tanhf2(cst[r]));                                 \
    }                                                                          \
    *(half4*)&hfr[(T) & 1][w >> 1][l][(w & 1) << 2] = hh;                      \
    LGKM_BARRIER();                                                            \
    if (((T) & 7) == 7 && tid == 0) /* consumption counter: relaxed ok */      \
      __hip_atomic_store(pY, (unsigned)((T) + 1), __ATOMIC_RELAXED,            \
                         __HIP_MEMORY_SCOPE_AGENT);                            \
  }

    for (int t = 0; t < NT; t += 2) {
      YSTEP(t, gA0, gA1, gA2, gA3);
      YSTEP(t + 1, gB0, gB1, gB2, gB3);
    }
#undef YSTEP
    {  // epilogue: FC of h1[NT-1] -> out[NT-1]
      const int rdk = (NT + 1) & 1;
      half8 b0 = *(const half8*)&hfr[rdk][0][l][0];
      half8 b1 = *(const half8*)&hfr[rdk][1][l][0];
      half8 b2 = *(const half8*)&hfr[rdk][2][l][0];
      half8 b3 = *(const half8*)&hfr[rdk][3][l][0];
      if (fcon) {
        f32x4 afc = fcbv;
        afc = MFMA(FCA[0], b0, afc); afc = MFMA(FCA[1], b1, afc);
        afc = MFMA(FCA[2], b2, afc); afc = MFMA(FCA[3], b3, afc);
        *(f32x4*)(outG + (size_t)(NT - 1) * 64) = afc;
      }
    }
  }
}

extern "C" void kernel_launch(void* const* d_in, const int* in_sizes, int n_in,
                              void* d_out, int out_size, void* d_ws, size_t ws_size,
                              hipStream_t stream) {
  const float* x     = (const float*)d_in[0];
  const float* w_ih0 = (const float*)d_in[1];
  const float* w_hh0 = (const float*)d_in[2];
  const float* w_ih1 = (const float*)d_in[3];
  const float* w_hh1 = (const float*)d_in[4];
  const float* b_ih  = (const float*)d_in[5];
  const float* b_hh  = (const float*)d_in[6];
  const float* fc_w  = (const float*)d_in[7];
  const float* fc_b  = (const float*)d_in[8];

  // ws: Xf 16MB | h0R 8MB | gxR 16MB | gyR 16MB | flags 4KB  (= 56MB+4KB)
  _Float16* Xf  = (_Float16*)d_ws;
  _Float16* h0R = (_Float16*)((char*)d_ws + (16u << 20));
  float* gxR    = (float*)((char*)d_ws + (24u << 20));
  float* gyR    = (float*)((char*)d_ws + (40u << 20));
  unsigned* flags = (unsigned*)((char*)d_ws + (56u << 20));

  (void)hipMemsetAsync(flags, 0, 4096, stream);
  prep_x<<<4096, 256, 0, stream>>>(x, Xf);
  lstm_main<<<24, 512, 0, stream>>>(w_ih0, w_hh0, w_ih1, w_hh1, b_ih, b_hh,
                                    fc_w, fc_b, Xf, h0R, gxR, gyR, flags,
                                    (float*)d_out);
}